// Round 15
// baseline (208.695 us; speedup 1.0000x reference)
//
#include <hip/hip_runtime.h>
#include <hip/hip_bf16.h>
#include <math.h>

#define SEQ 2048
#define NHEAD 24     // 3*H
#define CDIM 32
#define VDIM 128

typedef short bf16x8 __attribute__((ext_vector_type(8)));
typedef float f32x4 __attribute__((ext_vector_type(4)));

#define L2E 1.44269504088896f        // log2(e): folded into K so exp2 == exp
#define SQRT_L2E 1.20112240878645f   // sqrt(log2 e): rot logits get squared

#if __has_builtin(__builtin_amdgcn_exp2f)
#define EXP2(x) __builtin_amdgcn_exp2f(x)
#else
#define EXP2(x) exp2f(x)
#endif

// K B-frags, hi/lo split: [g][blk16(128)][part(2)][lane(64)][e(8)]
__device__ unsigned short g_kkp[(size_t)24 * 128 * 2 * 64 * 8];
// Q+V frags: [g][jt(32 x 64j)][frag(24)][lane(64)][e(8)]
__device__ unsigned short g_qv[(size_t)24 * 32 * 24 * 64 * 8];
// weights (w_values||w_nodes_kq rows): [fg(224*4)][part(2)][lane][e]
__device__ unsigned short g_wp[(size_t)224 * 4 * 2 * 64 * 8];
// nodes A-frags: [fg(128*4)][part(2)][lane][e]
__device__ unsigned short g_np[(size_t)128 * 4 * 2 * 64 * 8];
// per-head max|q| (heads 0..15 used), f32 bit pattern (>=0)
__device__ unsigned g_qmax[24];

__device__ __forceinline__ unsigned short f2b(float x) {   // RNE f32->bf16
  union { float f; unsigned u; } v; v.f = x;
  unsigned r = v.u + 0x7FFF + ((v.u >> 16) & 1);
  return (unsigned short)(r >> 16);
}
__device__ __forceinline__ float b2f(unsigned short u) {
  union { unsigned u32; float f; } x; x.u32 = ((unsigned)u) << 16; return x.f;
}
__device__ __forceinline__ unsigned pk2(float a, float b) {
  __hip_bfloat162 t = __float22bfloat162_rn(float2{a, b});
  union { __hip_bfloat162 h; unsigned u; } c; c.h = t; return c.u;
}
__device__ __forceinline__ unsigned long long pack64(const float* p) {
  return ((unsigned long long)pk2(p[2], p[3]) << 32) | pk2(p[0], p[1]);
}
__device__ __forceinline__ float bperm_f(int srclane, float v) {
  union { float f; int i; } u; u.f = v;
  u.i = __builtin_amdgcn_ds_bpermute(srclane * 4, u.i);
  return u.f;
}
__device__ __forceinline__ void gld16(const unsigned short* g, unsigned short* l) {
  __builtin_amdgcn_global_load_lds(
      (const __attribute__((address_space(1))) unsigned int*)g,
      (__attribute__((address_space(3))) unsigned int*)l, 16, 0, 0);
}

// ---------- merged: zero d_out + qmax init + hi/lo conversion of weights/nodes ----------
__global__ __launch_bounds__(256) void k_pre(const float* __restrict__ nodes,
                                             const float* __restrict__ w_v,
                                             const float* __restrict__ w_n,
                                             float* __restrict__ out) {
  const int bx = blockIdx.x;
  if (bx < 1024) {
    if (bx == 0 && threadIdx.x < 24) g_qmax[threadIdx.x] = 0u;
    out[bx * 256 + threadIdx.x] = 0.f;
    return;
  }
  const int bb = bx - 1024;                 // 0..351
  const int tid = bb * 256 + threadIdx.x;
  const int fg = tid >> 6, lane = tid & 63;
  const int e0 = (lane >> 4) * 8;
  const float* p;
  unsigned short* dst;
  if (bb < 224) {
    const int colblk = fg >> 2, ks = fg & 3;
    const int ocol = colblk * 16 + (lane & 15);
    const float* src = (ocol < 3072) ? (w_v + (size_t)ocol * 128)
                                     : (w_n + (size_t)(ocol - 3072) * 128);
    p = src + ks * 32 + e0;
    dst = g_wp + (size_t)fg * 1024;
  } else {
    const int fg2 = fg - 224 * 4;           // 0..511
    const int rowblk = fg2 >> 2, ks = fg2 & 3;
    p = nodes + (size_t)(rowblk * 16 + (lane & 15)) * 128 + ks * 32 + e0;
    dst = g_np + (size_t)fg2 * 1024;
  }
  float4 f0 = *(const float4*)p;
  float4 f1 = *(const float4*)(p + 4);
  float ff[8] = {f0.x, f0.y, f0.z, f0.w, f1.x, f1.y, f1.z, f1.w};
  bf16x8 hi, lo;
#pragma unroll
  for (int e = 0; e < 8; ++e) {
    unsigned short h2 = f2b(ff[e]);
    hi[e] = (short)h2;
    lo[e] = (short)f2b(ff[e] - b2f(h2));
  }
  *(bf16x8*)(dst + (size_t)lane * 8) = hi;
  *(bf16x8*)(dst + 512 + (size_t)lane * 8) = lo;
}

// ---------- pos/rot repack helper (validated) ----------
__device__ __forceinline__ void repack_store(const unsigned* __restrict__ res,
                                             int oh, int it16, int tx, int head_base) {
#pragma unroll
  for (int t2 = 0; t2 < 2; ++t2) {
    int cid = tx + t2 * 256;
    int hl  = cid >> 7;
    int kq  = (cid >> 6) & 1;
    int row = cid & 63;
    int m = row & 15;
    int ob = hl * 64 + kq * 32 + (row >> 4) * 8;
    bf16x8 hi, lo;
#pragma unroll
    for (int e = 0; e < 8; ++e) {
      unsigned pk = res[(ob + e) * 17 + m];
      hi[e] = (short)(pk >> 16);
      lo[e] = (short)(pk & 0xffff);
    }
    int gh = head_base + oh * 4 + hl;
    if (kq == 0) {
      size_t base = ((size_t)(gh * 128 + it16) * 2) * 512 + (size_t)row * 8;
      *(bf16x8*)(g_kkp + base) = hi;
      *(bf16x8*)(g_kkp + base + 512) = lo;
    } else {
      int jt = it16 >> 2, jb = it16 & 3;
      size_t base = (((size_t)gh * 32 + jt) * 24 + jb * 2) * 512 + (size_t)row * 8;
      *(bf16x8*)(g_qv + base) = hi;
      *(bf16x8*)(g_qv + base + 512) = lo;
    }
  }
}

// ---------- merged: MFMA projection (bx<1792) + pos/rot (bx>=1792), smem overlaid ----------
__global__ __launch_bounds__(256) void k_mid(const float* __restrict__ b_v,
                                             const float* __restrict__ b_n,
                                             const float* __restrict__ pos,
                                             const float* __restrict__ rot,
                                             const float* __restrict__ w_p,
                                             const float* __restrict__ b_p,
                                             const float* __restrict__ w_r) {
  __shared__ __align__(16) char smem[53248];
  const int bx = blockIdx.x;
  const int tx = threadIdx.x;

  if (bx < 1792) {
    // ======== proj: C = nodes @ [w_values; w_nodes_kq]^T + bias (validated r10) ========
    const int jt = bx & 31;           // 64-row tile
    const int bo = bx >> 5;           // 64-col tile, 0..55
    const bool is_kq = bo >= 48;
    const float* bsrc = is_kq ? b_n : b_v;
    const int o0b = is_kq ? (bo - 48) * 64 : bo * 64;
    const int w = tx >> 6, lane = tx & 63;
    const int m = lane & 15, quad = lane >> 4;

    unsigned short (*bst)[64][8] = (unsigned short(*)[64][8])smem;       // 32 KB
    float (*res)[64][20] = (float(*)[64][20])(smem + 32768);             // 20 KB

    const unsigned short* wp = g_wp + ((size_t)bo * 32 + w * 8) * 512 + (size_t)lane * 8;
#pragma unroll
    for (int s = 0; s < 8; ++s)
      gld16(wp + s * 512, &bst[w * 8 + s][0][0]);

    bf16x8 ah[4], al[4];
    const unsigned short* np = g_np + (size_t)(jt * 4 + w) * 4096 + (size_t)lane * 8;
#pragma unroll
    for (int ks = 0; ks < 4; ++ks) {
      ah[ks] = *(const bf16x8*)(np + ks * 1024);
      al[ks] = *(const bf16x8*)(np + ks * 1024 + 512);
    }
    __syncthreads();

    f32x4 C[4];
#pragma unroll
    for (int ob = 0; ob < 4; ++ob) {
      f32x4 acc = {0.f, 0.f, 0.f, 0.f};
#pragma unroll
      for (int ks = 0; ks < 4; ++ks) {
        bf16x8 bh = *(const bf16x8*)&bst[ob * 8 + ks * 2][lane][0];
        bf16x8 bl = *(const bf16x8*)&bst[ob * 8 + ks * 2 + 1][lane][0];
        acc = __builtin_amdgcn_mfma_f32_16x16x32_bf16(ah[ks], bh, acc, 0, 0, 0);
        acc = __builtin_amdgcn_mfma_f32_16x16x32_bf16(al[ks], bh, acc, 0, 0, 0);
        acc = __builtin_amdgcn_mfma_f32_16x16x32_bf16(ah[ks], bl, acc, 0, 0, 0);
      }
      C[ob] = acc;
    }
    float qpart[4] = {0.f, 0.f, 0.f, 0.f};   // per-r Σ over this thread's q-cols
#pragma unroll
    for (int ob = 0; ob < 4; ++ob) {
      float bias = bsrc[o0b + ob * 16 + m];
#pragma unroll
      for (int r = 0; r < 4; ++r) {
        float v = C[ob][r] + bias;
        res[w][ob * 16 + m][quad * 4 + r] = v;
        if (is_kq && ob >= 2) qpart[r] += v * v;   // q cols: o in [32,64)
      }
    }
    if (!is_kq) {
      const int g = bo >> 1, dbb = (bo & 1) * 4;
      const int jc = w >> 1, khb = (w & 1) * 2;
#pragma unroll
      for (int oct = 0; oct < 2; ++oct) {
        f32x4 v0 = *(const f32x4*)&res[w][quad * 16 + m][oct * 8];
        f32x4 v1 = *(const f32x4*)&res[w][quad * 16 + m][oct * 8 + 4];
        bf16x8 pk;
#pragma unroll
        for (int e = 0; e < 4; ++e) {
          pk[e]     = (short)f2b(v0[e]);
          pk[4 + e] = (short)f2b(v1[e]);
        }
        ((bf16x8*)g_qv)[(((size_t)g * 32 + jt) * 24 + 8 + jc * 8 + dbb + quad) * 64
                        + (khb + oct) * 16 + m] = pk;
      }
    } else {
      const int h = bo - 48;
      {   // K (L2E folded)
        bf16x8 hi, lo;
#pragma unroll
        for (int e = 0; e < 8; ++e) {
          float v = res[w][quad * 8 + e][m] * L2E;
          unsigned short h2 = f2b(v);
          hi[e] = (short)h2;
          lo[e] = (short)f2b(v - b2f(h2));
        }
        size_t base = ((size_t)(h * 128 + jt * 4 + w) * 2) * 512 + (size_t)(quad * 16 + m) * 8;
        *(bf16x8*)(g_kkp + base) = hi;
        *(bf16x8*)(g_kkp + base + 512) = lo;
      }
      {   // Q
        bf16x8 hi, lo;
#pragma unroll
        for (int e = 0; e < 8; ++e) {
          float v = res[w][32 + quad * 8 + e][m];
          unsigned short h2 = f2b(v);
          hi[e] = (short)h2;
          lo[e] = (short)f2b(v - b2f(h2));
        }
        size_t base = (((size_t)h * 32 + jt) * 24 + w * 2) * 512 + (size_t)(quad * 16 + m) * 8;
        *(bf16x8*)(g_qv + base) = hi;
        *(bf16x8*)(g_qv + base + 512) = lo;
      }
      // ---- per-head max|q| from registers: reduce over 16 m-lanes, max over j ----
#pragma unroll
      for (int r = 0; r < 4; ++r) {
        qpart[r] += __shfl_xor(qpart[r], 1);
        qpart[r] += __shfl_xor(qpart[r], 2);
        qpart[r] += __shfl_xor(qpart[r], 4);
        qpart[r] += __shfl_xor(qpart[r], 8);
      }
      float mx = fmaxf(fmaxf(qpart[0], qpart[1]), fmaxf(qpart[2], qpart[3]));
      mx = fmaxf(mx, __shfl_xor(mx, 16));
      mx = fmaxf(mx, __shfl_xor(mx, 32));
      if (lane == 0) atomicMax(&g_qmax[h], __float_as_uint(sqrtf(mx) * 1.0002f));
    }
  } else {
    // ======== pos/rot (validated r10), smem overlay ========
    const int r0 = bx - 1792;                // 0..511
    const int it16 = r0 & 127, oh = (r0 >> 7) & 1, br = r0 >> 8;
    const int i0 = it16 * 16;
    unsigned* res = (unsigned*)smem;                         // 17408 B
    float (*pf_sh)[8] = (float(*)[8])(smem + 17408);
    float (*rr_sh)[4] = (float(*)[4])(smem + 17920);

    if (br == 0) {
      if (tx < 48) {
        int r = tx / 3, t = tx - r * 3;
        float p = pos[(i0 + r) * 3 + t];
        pf_sh[r][t]     = cosf(6.283185307179586f * p);
        pf_sh[r][t + 3] = sinf(6.283185307179586f * p);
      }
    } else {
      if (tx < 64) {
        int r = tx >> 2, t = tx & 3;
        rr_sh[r][t] = rot[(i0 + r) * 4 + t];
      }
    }
    __syncthreads();

    const int og = tx & 63, ig = tx >> 6;
    if (br == 0) {
      float sq[4][4];
#pragma unroll
      for (int a = 0; a < 4; ++a)
#pragma unroll
        for (int b = 0; b < 4; ++b) sq[a][b] = 0.f;
#pragma unroll
      for (int oo = 0; oo < 4; ++oo) {
        int o = oh * 256 + oo * 64 + og;
        float bb = b_p[o];
        float w0 = w_p[o * 6 + 0], w1 = w_p[o * 6 + 1], w2 = w_p[o * 6 + 2];
        float w3 = w_p[o * 6 + 3], w4 = w_p[o * 6 + 4], w5 = w_p[o * 6 + 5];
        float sc = ((o & 63) < 32) ? L2E : 1.f;
#pragma unroll
        for (int ii = 0; ii < 4; ++ii) {
          int i = ig * 4 + ii;
          float v = bb + pf_sh[i][0] * w0 + pf_sh[i][1] * w1 + pf_sh[i][2] * w2
                       + pf_sh[i][3] * w3 + pf_sh[i][4] * w4 + pf_sh[i][5] * w5;
          v *= sc;
          if (og >= 32) sq[oo][ii] = v * v;        // q-col contribution
          unsigned short hi = f2b(v);
          unsigned short lo = f2b(v - b2f(hi));
          res[(oo * 64 + og) * 17 + i] = ((unsigned)hi << 16) | lo;
        }
      }
      // ---- per-head max|q|: sum over the 32 q-col lanes (closed xor group), max over j ----
#pragma unroll
      for (int oo = 0; oo < 4; ++oo) {
#pragma unroll
        for (int ii = 0; ii < 4; ++ii) {
          float s = sq[oo][ii];
          s += __shfl_xor(s, 1); s += __shfl_xor(s, 2);
          s += __shfl_xor(s, 4); s += __shfl_xor(s, 8);
          s += __shfl_xor(s, 16);
          sq[oo][ii] = s;
        }
        float mx = fmaxf(fmaxf(sq[oo][0], sq[oo][1]), fmaxf(sq[oo][2], sq[oo][3]));
        if (og == 32) atomicMax(&g_qmax[8 + oh * 4 + oo], __float_as_uint(sqrtf(mx) * 1.0002f));
      }
    } else {
#pragma unroll
      for (int oo = 0; oo < 4; ++oo) {
        int o = oh * 256 + oo * 64 + og;
        float w0 = w_r[o * 4 + 0], w1 = w_r[o * 4 + 1], w2 = w_r[o * 4 + 2], w3 = w_r[o * 4 + 3];
        float sc = ((o & 63) < 32) ? SQRT_L2E : 1.f;
#pragma unroll
        for (int ii = 0; ii < 4; ++ii) {
          int i = ig * 4 + ii;
          float v = (rr_sh[i][0] * w0 + rr_sh[i][1] * w1 + rr_sh[i][2] * w2 + rr_sh[i][3] * w3) * sc;
          unsigned short hi = f2b(v);
          unsigned short lo = f2b(v - b2f(hi));
          res[(oo * 64 + og) * 17 + i] = ((unsigned)hi << 16) | lo;
        }
      }
    }
    __syncthreads();
    repack_store(res, oh, it16, tx, 8 + br * 8);
  }
}

// ---------- MFMA flash attention: fixed-M fast path (heads 0..15), online for rot ----------
__global__ __launch_bounds__(256, 3) void k_attn(float* __restrict__ out) {
  const int it = blockIdx.x;            // 0..31
  const int g  = blockIdx.y;            // 0..23
  const int tx = threadIdx.x;
  const int w = tx >> 6, lane = tx & 63;
  const int quad = lane >> 4, n = lane & 15;
  const int iblk = it * 4 + w;

  __shared__ __align__(16) unsigned short stage[2][24][64][8];   // 48 KB
  __shared__ __align__(16) unsigned long long p_lds[4][64][2];   // 4 KB

  const bf16x8* kp = (const bf16x8*)g_kkp + (size_t)(g * 128 + iblk) * 2 * 64;
  const bf16x8 khi = kp[lane], klo = kp[64 + lane];

  f32x4 oacc[8];
#pragma unroll
  for (int db = 0; db < 8; ++db)
#pragma unroll
    for (int r = 0; r < 4; ++r) oacc[db][r] = 0.f;

  const bool is_rot = (g >= 16);
  float l_part = 0.f;
  const int pin = (lane & 56) | ((lane ^ (lane >> 3)) & 7);
  const int wrow0 = (quad >> 1) * 16 + n;
  const int wrow1 = wrow0 + 32;
  const int pr0 = (wrow0 & 56) | ((wrow0 ^ (wrow0 >> 3)) & 7);
  const int pr1 = (wrow1 & 56) | ((wrow1 ^ (wrow1 >> 3)) & 7);
  const int whalf = quad & 1;

  const unsigned short* qv = g_qv + ((size_t)g * 32 * 24 + w * 6) * 512 + (size_t)lane * 8;

#define STG(nb)                                          \
  { gld16(qv,             &stage[nb][w * 6 + 0][0][0]);  \
    gld16(qv + 512,       &stage[nb][w * 6 + 1][0][0]);  \
    gld16(qv + 1024,      &stage[nb][w * 6 + 2][0][0]);  \
    gld16(qv + 1536,      &stage[nb][w * 6 + 3][0][0]);  \
    gld16(qv + 2048,      &stage[nb][w * 6 + 4][0][0]);  \
    gld16(qv + 2560,      &stage[nb][w * 6 + 5][0][0]); }

  STG(0)

  bf16x8 a0 = {}, a1 = {};
  bf16x8 vprev[16];

  if (!is_rot) {
    // ======== fast path: fixed safe bound M from K registers + per-head qmax ========
    float sk = 0.f;
#pragma unroll
    for (int e = 0; e < 8; ++e) {
      float kv = b2f((unsigned short)khi[e]) + b2f((unsigned short)klo[e]);
      sk += kv * kv;
    }
    sk += __shfl_xor(sk, 16);
    sk += __shfl_xor(sk, 32);                   // lane n now has |k_{i=n}|^2 (L2E-scaled)
    const float M = sqrtf(sk) * 1.0002f * __uint_as_float(g_qmax[g]);
    const f32x4 sInit = {-M, -M, -M, -M};       // fold -M into MFMA C-init
    for (int jt = 0; jt < 32; ++jt) {
      const int buf = jt & 1;
      __syncthreads();
      if (jt) {
#pragma unroll
        for (int db = 0; db < 8; ++db)
          oacc[db] = __builtin_amdgcn_mfma_f32_16x16x32_bf16(a0, vprev[db], oacc[db], 0, 0, 0);
#pragma unroll
        for (int db = 0; db < 8; ++db)
          oacc[db] = __builtin_amdgcn_mfma_f32_16x16x32_bf16(a1, vprev[8 + db], oacc[db], 0, 0, 0);
      }
      qv += 24 * 512;
      if (jt < 31) STG(buf ^ 1)

      const bf16x8* st = (const bf16x8*)&stage[buf][0][0][0];
      f32x4 S[4];
#pragma unroll
      for (int jb = 0; jb < 4; ++jb) {
        bf16x8 qh = st[(jb * 2) * 64 + lane], ql = st[(jb * 2 + 1) * 64 + lane];
        f32x4 a = sInit;
        a = __builtin_amdgcn_mfma_f32_16x16x32_bf16(qh, khi, a, 0, 0, 0);
        a = __builtin_amdgcn_mfma_f32_16x16x32_bf16(ql, khi, a, 0, 0, 0);
        a = __builtin_amdgcn_mfma_f32_16x16x32_bf16(qh, klo, a, 0, 0, 0);
        S[jb] = a;
      }
      float p[4][4];
#pragma unroll
      for (int jb = 0; jb < 4; ++jb)
#pragma unroll
        for (int r = 0; r < 4; ++r) {
          p[jb][r] = EXP2(S[jb][r]);
          l_part += p[jb][r];
        }
      p_lds[w][pr0][whalf] = pack64(p[0]);
      p_lds[w][pr1][whalf] = pack64(p[1]);
      a0 = *(const bf16x8*)&p_lds[w][pin][0];
      p_lds[w][pr0][whalf] = pack64(p[2]);
      p_lds[w][pr1][whalf] = pack64(p[3]);
      a1 = *(const bf16x8*)&p_lds[w][pin][0];
#pragma unroll
      for (int f = 0; f < 16; ++f) vprev[f] = st[(8 + f) * 64 + lane];
    }
  } else {
    // ======== rot heads: r13 online-softmax path ========
    float m_run = -3.0e38f;
    for (int jt = 0; jt < 32; ++jt) {
      const int buf = jt & 1;
      __syncthreads();
      if (jt) {
#pragma unroll
        for (int db = 0; db < 8; ++db)
          oacc[db] = __builtin_amdgcn_mfma_f32_16x16x32_bf16(a0, vprev[db], oacc[db], 0, 0, 0);
#pragma unroll
        for (int db = 0; db < 8; ++db)
          oacc[db] = __builtin_amdgcn_mfma_f32_16x16x32_bf16(a1, vprev[8 + db], oacc[db], 0, 0, 0);
      }
      qv += 24 * 512;
      if (jt < 31) STG(buf ^ 1)

      const bf16x8* st = (const bf16x8*)&stage[buf][0][0][0];
      f32x4 S[4];
#pragma unroll
      for (int jb = 0; jb < 4; ++jb) {
        bf16x8 qh = st[(jb * 2) * 64 + lane], ql = st[(jb * 2 + 1) * 64 + lane];
        f32x4 a = {0.f, 0.f, 0.f, 0.f};
        a = __builtin_amdgcn_mfma_f32_16x16x32_bf16(qh, khi, a, 0, 0, 0);
        a = __builtin_amdgcn_mfma_f32_16x16x32_bf16(ql, khi, a, 0, 0, 0);
        a = __builtin_amdgcn_mfma_f32_16x16x32_bf16(qh, klo, a, 0, 0, 0);
        S[jb] = a;
      }
#pragma unroll
      for (int jb = 0; jb < 4; ++jb)
#pragma unroll
        for (int r = 0; r < 4; ++r) S[jb][r] *= S[jb][r];
      float mloc = S[0][0];
#pragma unroll
      for (int jb = 0; jb < 4; ++jb)
#pragma unroll
        for (int r = 0; r < 4; ++r) mloc = fmaxf(mloc, S[jb][r]);
      if (__ballot(mloc > m_run)) {
        float mb = fmaxf(mloc, __shfl_xor(mloc, 16));
        mb = fmaxf(mb, __shfl_xor(mb, 32));
        float m_new = fmaxf(m_run, mb);
        float alpha = EXP2(m_run - m_new);
        m_run = m_new;
        l_part *= alpha;
        f32x4 av;
#pragma unroll
        for (int r = 0; r < 4; ++r) av[r] = bperm_f(quad * 4 + r, alpha);
#pragma unroll
        for (int db = 0; db < 8; ++db) {
          oacc[db][0] *= av[0]; oacc[db][1] *= av[1];
          oacc[db][2] *= av[2]; oacc[db][3] *= av[3];
        }
      }
      float p[4][4];
#pragma unroll
      for (int jb = 0; jb < 4; ++jb)
#pragma unroll
        for (int r = 0; r < 4; ++r) {
          p[jb][r] = EXP2(S[jb][r] - m_run);
          l_part += p[jb][r];
        }
      p_lds[w][pr0][whalf] = pack64(p[0]);
      p_lds[w][pr1][whalf] = pack64(p[1]);
      a0 = *(const bf16x8*)&p_lds[w][pin][0];
      p_lds[w][pr0][whalf] = pack64(p[2]);
      p_lds[w][pr1][whalf] = pack64(p[3]);
      a1 = *(const bf16x8*)&p_lds[w][pin][0];
#pragma unroll
      for (int f = 0; f < 16; ++f) vprev[f] = st[(8 + f) * 64 + lane];
    }
  }
  // --- final PV(31)
#pragma unroll
  for (int db = 0; db < 8; ++db)
    oacc[db] = __builtin_amdgcn_mfma_f32_16x16x32_bf16(a0, vprev[db], oacc[db], 0, 0, 0);
#pragma unroll
  for (int db = 0; db < 8; ++db)
    oacc[db] = __builtin_amdgcn_mfma_f32_16x16x32_bf16(a1, vprev[8 + db], oacc[db], 0, 0, 0);

  // --- epilogue: l reduction, column->row broadcast, scaled atomics
  float l = l_part;
  l += __shfl_xor(l, 16);
  l += __shfl_xor(l, 32);
  float linv = 1.f / l;
  f32x4 lv;
#pragma unroll
  for (int r = 0; r < 4; ++r) lv[r] = bperm_f(quad * 4 + r, linv);
  const int ibase = it * 64 + w * 16 + quad * 4;
#pragma unroll
  for (int db = 0; db < 8; ++db)
#pragma unroll
    for (int r = 0; r < 4; ++r)
      atomicAdd(&out[(size_t)(ibase + r) * VDIM + db * 16 + n], oacc[db][r] * lv[r]);
}

extern "C" void kernel_launch(void* const* d_in, const int* in_sizes, int n_in,
                              void* d_out, int out_size, void* d_ws, size_t ws_size,
                              hipStream_t stream) {
  const float* nodes = (const float*)d_in[0];
  const float* pos   = (const float*)d_in[1];
  const float* rot   = (const float*)d_in[2];
  const float* w_n   = (const float*)d_in[3];
  const float* b_n   = (const float*)d_in[4];
  const float* w_p   = (const float*)d_in[5];
  const float* b_p   = (const float*)d_in[6];
  const float* w_r   = (const float*)d_in[7];
  const float* w_v   = (const float*)d_in[8];
  const float* b_v   = (const float*)d_in[9];
  float* out = (float*)d_out;

  k_pre<<<dim3(1024 + 352), 256, 0, stream>>>(nodes, w_v, w_n, out);
  k_mid<<<dim3(1792 + 512), 256, 0, stream>>>(b_v, b_n, pos, rot, w_p, b_p, w_r);
  k_attn<<<dim3(32, NHEAD), 256, 0, stream>>>(out);
}

// Round 16
// 207.820 us; speedup vs baseline: 1.0042x; 1.0042x over previous
//
#include <hip/hip_runtime.h>
#include <hip/hip_bf16.h>
#include <math.h>

#define SEQ 2048
#define NHEAD 24     // 3*H
#define CDIM 32
#define VDIM 128

typedef short bf16x8 __attribute__((ext_vector_type(8)));
typedef float f32x4 __attribute__((ext_vector_type(4)));

#define L2E 1.44269504088896f        // log2(e): folded into K so exp2 == exp
#define SQRT_L2E 1.20112240878645f   // sqrt(log2 e): rot logits get squared

#if __has_builtin(__builtin_amdgcn_exp2f)
#define EXP2(x) __builtin_amdgcn_exp2f(x)
#else
#define EXP2(x) exp2f(x)
#endif

// K B-frags, hi/lo split: [g][blk16(128)][part(2)][lane(64)][e(8)]
__device__ unsigned short g_kkp[(size_t)24 * 128 * 2 * 64 * 8];
// Q+V frags: [g][jt(32 x 64j)][frag(24)][lane(64)][e(8)]
__device__ unsigned short g_qv[(size_t)24 * 32 * 24 * 64 * 8];
// weights (w_values||w_nodes_kq rows): [fg(224*4)][part(2)][lane][e]
__device__ unsigned short g_wp[(size_t)224 * 4 * 2 * 64 * 8];
// nodes A-frags: [fg(128*4)][part(2)][lane][e]
__device__ unsigned short g_np[(size_t)128 * 4 * 2 * 64 * 8];
// per-head max|q| (heads 0..15 used), f32 bit pattern (>=0)
__device__ unsigned g_qmax[24];

__device__ __forceinline__ unsigned short f2b(float x) {   // RNE f32->bf16
  union { float f; unsigned u; } v; v.f = x;
  unsigned r = v.u + 0x7FFF + ((v.u >> 16) & 1);
  return (unsigned short)(r >> 16);
}
__device__ __forceinline__ float b2f(unsigned short u) {
  union { unsigned u32; float f; } x; x.u32 = ((unsigned)u) << 16; return x.f;
}
__device__ __forceinline__ unsigned pk2(float a, float b) {
  __hip_bfloat162 t = __float22bfloat162_rn(float2{a, b});
  union { __hip_bfloat162 h; unsigned u; } c; c.h = t; return c.u;
}
__device__ __forceinline__ unsigned long long pack64(const float* p) {
  return ((unsigned long long)pk2(p[2], p[3]) << 32) | pk2(p[0], p[1]);
}
__device__ __forceinline__ float bperm_f(int srclane, float v) {
  union { float f; int i; } u; u.f = v;
  u.i = __builtin_amdgcn_ds_bpermute(srclane * 4, u.i);
  return u.f;
}
__device__ __forceinline__ void gld16(const unsigned short* g, unsigned short* l) {
  __builtin_amdgcn_global_load_lds(
      (const __attribute__((address_space(1))) unsigned int*)g,
      (__attribute__((address_space(3))) unsigned int*)l, 16, 0, 0);
}

// ---------- merged: zero d_out + qmax init + hi/lo conversion of weights/nodes ----------
__global__ __launch_bounds__(256) void k_pre(const float* __restrict__ nodes,
                                             const float* __restrict__ w_v,
                                             const float* __restrict__ w_n,
                                             float* __restrict__ out) {
  const int bx = blockIdx.x;
  if (bx < 1024) {
    if (bx == 0 && threadIdx.x < 24) g_qmax[threadIdx.x] = 0u;
    out[bx * 256 + threadIdx.x] = 0.f;
    return;
  }
  const int bb = bx - 1024;                 // 0..351
  const int tid = bb * 256 + threadIdx.x;
  const int fg = tid >> 6, lane = tid & 63;
  const int e0 = (lane >> 4) * 8;
  const float* p;
  unsigned short* dst;
  if (bb < 224) {
    const int colblk = fg >> 2, ks = fg & 3;
    const int ocol = colblk * 16 + (lane & 15);
    const float* src = (ocol < 3072) ? (w_v + (size_t)ocol * 128)
                                     : (w_n + (size_t)(ocol - 3072) * 128);
    p = src + ks * 32 + e0;
    dst = g_wp + (size_t)fg * 1024;
  } else {
    const int fg2 = fg - 224 * 4;           // 0..511
    const int rowblk = fg2 >> 2, ks = fg2 & 3;
    p = nodes + (size_t)(rowblk * 16 + (lane & 15)) * 128 + ks * 32 + e0;
    dst = g_np + (size_t)fg2 * 1024;
  }
  float4 f0 = *(const float4*)p;
  float4 f1 = *(const float4*)(p + 4);
  float ff[8] = {f0.x, f0.y, f0.z, f0.w, f1.x, f1.y, f1.z, f1.w};
  bf16x8 hi, lo;
#pragma unroll
  for (int e = 0; e < 8; ++e) {
    unsigned short h2 = f2b(ff[e]);
    hi[e] = (short)h2;
    lo[e] = (short)f2b(ff[e] - b2f(h2));
  }
  *(bf16x8*)(dst + (size_t)lane * 8) = hi;
  *(bf16x8*)(dst + 512 + (size_t)lane * 8) = lo;
}

// ---------- pos/rot repack helper (validated) ----------
__device__ __forceinline__ void repack_store(const unsigned* __restrict__ res,
                                             int oh, int it16, int tx, int head_base) {
#pragma unroll
  for (int t2 = 0; t2 < 2; ++t2) {
    int cid = tx + t2 * 256;
    int hl  = cid >> 7;
    int kq  = (cid >> 6) & 1;
    int row = cid & 63;
    int m = row & 15;
    int ob = hl * 64 + kq * 32 + (row >> 4) * 8;
    bf16x8 hi, lo;
#pragma unroll
    for (int e = 0; e < 8; ++e) {
      unsigned pk = res[(ob + e) * 17 + m];
      hi[e] = (short)(pk >> 16);
      lo[e] = (short)(pk & 0xffff);
    }
    int gh = head_base + oh * 4 + hl;
    if (kq == 0) {
      size_t base = ((size_t)(gh * 128 + it16) * 2) * 512 + (size_t)row * 8;
      *(bf16x8*)(g_kkp + base) = hi;
      *(bf16x8*)(g_kkp + base + 512) = lo;
    } else {
      int jt = it16 >> 2, jb = it16 & 3;
      size_t base = (((size_t)gh * 32 + jt) * 24 + jb * 2) * 512 + (size_t)row * 8;
      *(bf16x8*)(g_qv + base) = hi;
      *(bf16x8*)(g_qv + base + 512) = lo;
    }
  }
}

// ---------- merged: MFMA projection (bx<1792) + pos/rot (bx>=1792), smem overlaid ----------
__global__ __launch_bounds__(256) void k_mid(const float* __restrict__ b_v,
                                             const float* __restrict__ b_n,
                                             const float* __restrict__ pos,
                                             const float* __restrict__ rot,
                                             const float* __restrict__ w_p,
                                             const float* __restrict__ b_p,
                                             const float* __restrict__ w_r) {
  __shared__ __align__(16) char smem[53248];
  const int bx = blockIdx.x;
  const int tx = threadIdx.x;

  if (bx < 1792) {
    // ======== proj: C = nodes @ [w_values; w_nodes_kq]^T + bias (validated r10) ========
    const int jt = bx & 31;           // 64-row tile
    const int bo = bx >> 5;           // 64-col tile, 0..55
    const bool is_kq = bo >= 48;
    const float* bsrc = is_kq ? b_n : b_v;
    const int o0b = is_kq ? (bo - 48) * 64 : bo * 64;
    const int w = tx >> 6, lane = tx & 63;
    const int m = lane & 15, quad = lane >> 4;

    unsigned short (*bst)[64][8] = (unsigned short(*)[64][8])smem;       // 32 KB
    float (*res)[64][20] = (float(*)[64][20])(smem + 32768);             // 20 KB

    const unsigned short* wp = g_wp + ((size_t)bo * 32 + w * 8) * 512 + (size_t)lane * 8;
#pragma unroll
    for (int s = 0; s < 8; ++s)
      gld16(wp + s * 512, &bst[w * 8 + s][0][0]);

    bf16x8 ah[4], al[4];
    const unsigned short* np = g_np + (size_t)(jt * 4 + w) * 4096 + (size_t)lane * 8;
#pragma unroll
    for (int ks = 0; ks < 4; ++ks) {
      ah[ks] = *(const bf16x8*)(np + ks * 1024);
      al[ks] = *(const bf16x8*)(np + ks * 1024 + 512);
    }
    __syncthreads();

    f32x4 C[4];
#pragma unroll
    for (int ob = 0; ob < 4; ++ob) {
      f32x4 acc = {0.f, 0.f, 0.f, 0.f};
#pragma unroll
      for (int ks = 0; ks < 4; ++ks) {
        bf16x8 bh = *(const bf16x8*)&bst[ob * 8 + ks * 2][lane][0];
        bf16x8 bl = *(const bf16x8*)&bst[ob * 8 + ks * 2 + 1][lane][0];
        acc = __builtin_amdgcn_mfma_f32_16x16x32_bf16(ah[ks], bh, acc, 0, 0, 0);
        acc = __builtin_amdgcn_mfma_f32_16x16x32_bf16(al[ks], bh, acc, 0, 0, 0);
        acc = __builtin_amdgcn_mfma_f32_16x16x32_bf16(ah[ks], bl, acc, 0, 0, 0);
      }
      C[ob] = acc;
    }
    float qpart[4] = {0.f, 0.f, 0.f, 0.f};   // per-r Σ over this thread's q-cols
#pragma unroll
    for (int ob = 0; ob < 4; ++ob) {
      float bias = bsrc[o0b + ob * 16 + m];
#pragma unroll
      for (int r = 0; r < 4; ++r) {
        float v = C[ob][r] + bias;
        res[w][ob * 16 + m][quad * 4 + r] = v;
        if (is_kq && ob >= 2) qpart[r] += v * v;   // q cols: o in [32,64)
      }
    }
    if (!is_kq) {
      const int g = bo >> 1, dbb = (bo & 1) * 4;
      const int jc = w >> 1, khb = (w & 1) * 2;
#pragma unroll
      for (int oct = 0; oct < 2; ++oct) {
        f32x4 v0 = *(const f32x4*)&res[w][quad * 16 + m][oct * 8];
        f32x4 v1 = *(const f32x4*)&res[w][quad * 16 + m][oct * 8 + 4];
        bf16x8 pk;
#pragma unroll
        for (int e = 0; e < 4; ++e) {
          pk[e]     = (short)f2b(v0[e]);
          pk[4 + e] = (short)f2b(v1[e]);
        }
        ((bf16x8*)g_qv)[(((size_t)g * 32 + jt) * 24 + 8 + jc * 8 + dbb + quad) * 64
                        + (khb + oct) * 16 + m] = pk;
      }
    } else {
      const int h = bo - 48;
      {   // K (L2E folded)
        bf16x8 hi, lo;
#pragma unroll
        for (int e = 0; e < 8; ++e) {
          float v = res[w][quad * 8 + e][m] * L2E;
          unsigned short h2 = f2b(v);
          hi[e] = (short)h2;
          lo[e] = (short)f2b(v - b2f(h2));
        }
        size_t base = ((size_t)(h * 128 + jt * 4 + w) * 2) * 512 + (size_t)(quad * 16 + m) * 8;
        *(bf16x8*)(g_kkp + base) = hi;
        *(bf16x8*)(g_kkp + base + 512) = lo;
      }
      {   // Q
        bf16x8 hi, lo;
#pragma unroll
        for (int e = 0; e < 8; ++e) {
          float v = res[w][32 + quad * 8 + e][m];
          unsigned short h2 = f2b(v);
          hi[e] = (short)h2;
          lo[e] = (short)f2b(v - b2f(h2));
        }
        size_t base = (((size_t)h * 32 + jt) * 24 + w * 2) * 512 + (size_t)(quad * 16 + m) * 8;
        *(bf16x8*)(g_qv + base) = hi;
        *(bf16x8*)(g_qv + base + 512) = lo;
      }
      // ---- per-head max|q| from registers: reduce over 16 m-lanes, max over j ----
#pragma unroll
      for (int r = 0; r < 4; ++r) {
        qpart[r] += __shfl_xor(qpart[r], 1);
        qpart[r] += __shfl_xor(qpart[r], 2);
        qpart[r] += __shfl_xor(qpart[r], 4);
        qpart[r] += __shfl_xor(qpart[r], 8);
      }
      float mx = fmaxf(fmaxf(qpart[0], qpart[1]), fmaxf(qpart[2], qpart[3]));
      mx = fmaxf(mx, __shfl_xor(mx, 16));
      mx = fmaxf(mx, __shfl_xor(mx, 32));
      if (lane == 0) atomicMax(&g_qmax[h], __float_as_uint(sqrtf(mx) * 1.0002f));
    }
  } else {
    // ======== pos/rot (validated r10), smem overlay ========
    const int r0 = bx - 1792;                // 0..511
    const int it16 = r0 & 127, oh = (r0 >> 7) & 1, br = r0 >> 8;
    const int i0 = it16 * 16;
    unsigned* res = (unsigned*)smem;                         // 17408 B
    float (*pf_sh)[8] = (float(*)[8])(smem + 17408);
    float (*rr_sh)[4] = (float(*)[4])(smem + 17920);

    if (br == 0) {
      if (tx < 48) {
        int r = tx / 3, t = tx - r * 3;
        float p = pos[(i0 + r) * 3 + t];
        pf_sh[r][t]     = cosf(6.283185307179586f * p);
        pf_sh[r][t + 3] = sinf(6.283185307179586f * p);
      }
    } else {
      if (tx < 64) {
        int r = tx >> 2, t = tx & 3;
        rr_sh[r][t] = rot[(i0 + r) * 4 + t];
      }
    }
    __syncthreads();

    const int og = tx & 63, ig = tx >> 6;
    if (br == 0) {
      float sq[4][4];
#pragma unroll
      for (int a = 0; a < 4; ++a)
#pragma unroll
        for (int b = 0; b < 4; ++b) sq[a][b] = 0.f;
#pragma unroll
      for (int oo = 0; oo < 4; ++oo) {
        int o = oh * 256 + oo * 64 + og;
        float bb = b_p[o];
        float w0 = w_p[o * 6 + 0], w1 = w_p[o * 6 + 1], w2 = w_p[o * 6 + 2];
        float w3 = w_p[o * 6 + 3], w4 = w_p[o * 6 + 4], w5 = w_p[o * 6 + 5];
        float sc = ((o & 63) < 32) ? L2E : 1.f;
#pragma unroll
        for (int ii = 0; ii < 4; ++ii) {
          int i = ig * 4 + ii;
          float v = bb + pf_sh[i][0] * w0 + pf_sh[i][1] * w1 + pf_sh[i][2] * w2
                       + pf_sh[i][3] * w3 + pf_sh[i][4] * w4 + pf_sh[i][5] * w5;
          v *= sc;
          if (og >= 32) sq[oo][ii] = v * v;        // q-col contribution
          unsigned short hi = f2b(v);
          unsigned short lo = f2b(v - b2f(hi));
          res[(oo * 64 + og) * 17 + i] = ((unsigned)hi << 16) | lo;
        }
      }
      // ---- per-head max|q|: sum over the 32 q-col lanes (closed xor group), max over j ----
#pragma unroll
      for (int oo = 0; oo < 4; ++oo) {
#pragma unroll
        for (int ii = 0; ii < 4; ++ii) {
          float s = sq[oo][ii];
          s += __shfl_xor(s, 1); s += __shfl_xor(s, 2);
          s += __shfl_xor(s, 4); s += __shfl_xor(s, 8);
          s += __shfl_xor(s, 16);
          sq[oo][ii] = s;
        }
        float mx = fmaxf(fmaxf(sq[oo][0], sq[oo][1]), fmaxf(sq[oo][2], sq[oo][3]));
        if (og == 32) atomicMax(&g_qmax[8 + oh * 4 + oo], __float_as_uint(sqrtf(mx) * 1.0002f));
      }
    } else {
#pragma unroll
      for (int oo = 0; oo < 4; ++oo) {
        int o = oh * 256 + oo * 64 + og;
        float w0 = w_r[o * 4 + 0], w1 = w_r[o * 4 + 1], w2 = w_r[o * 4 + 2], w3 = w_r[o * 4 + 3];
        float sc = ((o & 63) < 32) ? SQRT_L2E : 1.f;
#pragma unroll
        for (int ii = 0; ii < 4; ++ii) {
          int i = ig * 4 + ii;
          float v = (rr_sh[i][0] * w0 + rr_sh[i][1] * w1 + rr_sh[i][2] * w2 + rr_sh[i][3] * w3) * sc;
          unsigned short hi = f2b(v);
          unsigned short lo = f2b(v - b2f(hi));
          res[(oo * 64 + og) * 17 + i] = ((unsigned)hi << 16) | lo;
        }
      }
    }
    __syncthreads();
    repack_store(res, oh, it16, tx, 8 + br * 8);
  }
}

// ---------- MFMA flash attention: fixed-M fast path (heads 0..15), online for rot ----------
__global__ __launch_bounds__(256, 3) void k_attn(float* __restrict__ out) {
  const int it = blockIdx.x;            // 0..31
  const int g  = blockIdx.y;            // 0..23
  const int tx = threadIdx.x;
  const int w = tx >> 6, lane = tx & 63;
  const int quad = lane >> 4, n = lane & 15;
  const int iblk = it * 4 + w;

  __shared__ __align__(16) unsigned short stage[2][24][64][8];   // 48 KB
  __shared__ __align__(16) unsigned long long p_lds[4][64][2];   // 4 KB

  const bf16x8* kp = (const bf16x8*)g_kkp + (size_t)(g * 128 + iblk) * 2 * 64;
  const bf16x8 khi = kp[lane], klo = kp[64 + lane];

  f32x4 oacc[8];
#pragma unroll
  for (int db = 0; db < 8; ++db)
#pragma unroll
    for (int r = 0; r < 4; ++r) oacc[db][r] = 0.f;

  const bool is_rot = (g >= 16);
  float l_part = 0.f;
  const int pin = (lane & 56) | ((lane ^ (lane >> 3)) & 7);
  const int wrow0 = (quad >> 1) * 16 + n;
  const int wrow1 = wrow0 + 32;
  const int pr0 = (wrow0 & 56) | ((wrow0 ^ (wrow0 >> 3)) & 7);
  const int pr1 = (wrow1 & 56) | ((wrow1 ^ (wrow1 >> 3)) & 7);
  const int whalf = quad & 1;

  const unsigned short* qv = g_qv + ((size_t)g * 32 * 24 + w * 6) * 512 + (size_t)lane * 8;

#define STG(nb)                                          \
  { gld16(qv,             &stage[nb][w * 6 + 0][0][0]);  \
    gld16(qv + 512,       &stage[nb][w * 6 + 1][0][0]);  \
    gld16(qv + 1024,      &stage[nb][w * 6 + 2][0][0]);  \
    gld16(qv + 1536,      &stage[nb][w * 6 + 3][0][0]);  \
    gld16(qv + 2048,      &stage[nb][w * 6 + 4][0][0]);  \
    gld16(qv + 2560,      &stage[nb][w * 6 + 5][0][0]); }

  STG(0)

  bf16x8 a0 = {}, a1 = {};
  bf16x8 vprev[16];

  if (!is_rot) {
    // ======== fast path: fixed safe bound M from K registers + per-head qmax ========
    float sk = 0.f;
#pragma unroll
    for (int e = 0; e < 8; ++e) {
      float kv = b2f((unsigned short)khi[e]) + b2f((unsigned short)klo[e]);
      sk += kv * kv;
    }
    sk += __shfl_xor(sk, 16);
    sk += __shfl_xor(sk, 32);                   // lane n now has |k_{i=n}|^2 (L2E-scaled)
    const float M = sqrtf(sk) * 1.0002f * __uint_as_float(g_qmax[g]);
    const f32x4 sInit = {-M, -M, -M, -M};       // fold -M into MFMA C-init
    for (int jt = 0; jt < 32; ++jt) {
      const int buf = jt & 1;
      __syncthreads();
      if (jt) {
#pragma unroll
        for (int db = 0; db < 8; ++db)
          oacc[db] = __builtin_amdgcn_mfma_f32_16x16x32_bf16(a0, vprev[db], oacc[db], 0, 0, 0);
#pragma unroll
        for (int db = 0; db < 8; ++db)
          oacc[db] = __builtin_amdgcn_mfma_f32_16x16x32_bf16(a1, vprev[8 + db], oacc[db], 0, 0, 0);
      }
      qv += 24 * 512;
      if (jt < 31) STG(buf ^ 1)

      const bf16x8* st = (const bf16x8*)&stage[buf][0][0][0];
      f32x4 S[4];
#pragma unroll
      for (int jb = 0; jb < 4; ++jb) {
        bf16x8 qh = st[(jb * 2) * 64 + lane], ql = st[(jb * 2 + 1) * 64 + lane];
        f32x4 a = sInit;
        a = __builtin_amdgcn_mfma_f32_16x16x32_bf16(qh, khi, a, 0, 0, 0);
        a = __builtin_amdgcn_mfma_f32_16x16x32_bf16(ql, khi, a, 0, 0, 0);
        a = __builtin_amdgcn_mfma_f32_16x16x32_bf16(qh, klo, a, 0, 0, 0);
        S[jb] = a;
      }
      float p[4][4];
#pragma unroll
      for (int jb = 0; jb < 4; ++jb)
#pragma unroll
        for (int r = 0; r < 4; ++r) {
          p[jb][r] = EXP2(S[jb][r]);
          l_part += p[jb][r];
        }
      p_lds[w][pr0][whalf] = pack64(p[0]);
      p_lds[w][pr1][whalf] = pack64(p[1]);
      a0 = *(const bf16x8*)&p_lds[w][pin][0];
      p_lds[w][pr0][whalf] = pack64(p[2]);
      p_lds[w][pr1][whalf] = pack64(p[3]);
      a1 = *(const bf16x8*)&p_lds[w][pin][0];
#pragma unroll
      for (int f = 0; f < 16; ++f) vprev[f] = st[(8 + f) * 64 + lane];
    }
  } else {
    // ======== rot heads: r13 online-softmax path ========
    float m_run = -3.0e38f;
    for (int jt = 0; jt < 32; ++jt) {
      const int buf = jt & 1;
      __syncthreads();
      if (jt) {
#pragma unroll
        for (int db = 0; db < 8; ++db)
          oacc[db] = __builtin_amdgcn_mfma_f32_16x16x32_bf16(a0, vprev[db], oacc[db], 0, 0, 0);
#pragma unroll
        for (int db = 0; db < 8; ++db)
          oacc[db] = __builtin_amdgcn_mfma_f32_16x16x32_bf16(a1, vprev[8 + db], oacc[db], 0, 0, 0);
      }
      qv += 24 * 512;
      if (jt < 31) STG(buf ^ 1)

      const bf16x8* st = (const bf16x8*)&stage[buf][0][0][0];
      f32x4 S[4];
#pragma unroll
      for (int jb = 0; jb < 4; ++jb) {
        bf16x8 qh = st[(jb * 2) * 64 + lane], ql = st[(jb * 2 + 1) * 64 + lane];
        f32x4 a = {0.f, 0.f, 0.f, 0.f};
        a = __builtin_amdgcn_mfma_f32_16x16x32_bf16(qh, khi, a, 0, 0, 0);
        a = __builtin_amdgcn_mfma_f32_16x16x32_bf16(ql, khi, a, 0, 0, 0);
        a = __builtin_amdgcn_mfma_f32_16x16x32_bf16(qh, klo, a, 0, 0, 0);
        S[jb] = a;
      }
#pragma unroll
      for (int jb = 0; jb < 4; ++jb)
#pragma unroll
        for (int r = 0; r < 4; ++r) S[jb][r] *= S[jb][r];
      float mloc = S[0][0];
#pragma unroll
      for (int jb = 0; jb < 4; ++jb)
#pragma unroll
        for (int r = 0; r < 4; ++r) mloc = fmaxf(mloc, S[jb][r]);
      if (__ballot(mloc > m_run)) {
        float mb = fmaxf(mloc, __shfl_xor(mloc, 16));
        mb = fmaxf(mb, __shfl_xor(mb, 32));
        float m_new = fmaxf(m_run, mb);
        float alpha = EXP2(m_run - m_new);
        m_run = m_new;
        l_part *= alpha;
        f32x4 av;
#pragma unroll
        for (int r = 0; r < 4; ++r) av[r] = bperm_f(quad * 4 + r, alpha);
#pragma unroll
        for (int db = 0; db < 8; ++db) {
          oacc[db][0] *= av[0]; oacc[db][1] *= av[1];
          oacc[db][2] *= av[2]; oacc[db][3] *= av[3];
        }
      }
      float p[4][4];
#pragma unroll
      for (int jb = 0; jb < 4; ++jb)
#pragma unroll
        for (int r = 0; r < 4; ++r) {
          p[jb][r] = EXP2(S[jb][r] - m_run);
          l_part += p[jb][r];
        }
      p_lds[w][pr0][whalf] = pack64(p[0]);
      p_lds[w][pr1][whalf] = pack64(p[1]);
      a0 = *(const bf16x8*)&p_lds[w][pin][0];
      p_lds[w][pr0][whalf] = pack64(p[2]);
      p_lds[w][pr1][whalf] = pack64(p[3]);
      a1 = *(const bf16x8*)&p_lds[w][pin][0];
#pragma unroll
      for (int f = 0; f < 16; ++f) vprev[f] = st[(8 + f) * 64 + lane];
    }
  }
  // --- final PV(31)
#pragma unroll
  for (int db = 0; db < 8; ++db)
    oacc[db] = __builtin_amdgcn_mfma_f32_16x16x32_bf16(a0, vprev[db], oacc[db], 0, 0, 0);
#pragma unroll
  for (int db = 0; db < 8; ++db)
    oacc[db] = __builtin_amdgcn_mfma_f32_16x16x32_bf16(a1, vprev[8 + db], oacc[db], 0, 0, 0);

  // --- epilogue: l reduction, column->row broadcast, scaled atomics
  float l = l_part;
  l += __shfl_xor(l, 16);
  l += __shfl_xor(l, 32);
  float linv = 1.f / l;
  f32x4 lv;
#pragma unroll
  for (int r = 0; r < 4; ++r) lv[r] = bperm_f(quad * 4 + r, linv);
  const int ibase = it * 64 + w * 16 + quad * 4;
#pragma unroll
  for (int db = 0; db < 8; ++db)
#pragma unroll
    for (int r = 0; r < 4; ++r)
      atomicAdd(&out[(size_t)(ibase + r) * VDIM + db * 16 + n], oacc[db][r] * lv[r]);
}

extern "C" void kernel_launch(void* const* d_in, const int* in_sizes, int n_in,
                              void* d_out, int out_size, void* d_ws, size_t ws_size,
                              hipStream_t stream) {
  const float* nodes = (const float*)d_in[0];
  const float* pos   = (const float*)d_in[1];
  const float* rot   = (const float*)d_in[2];
  const float* w_n   = (const float*)d_in[3];
  const float* b_n   = (const float*)d_in[4];
  const float* w_p   = (const float*)d_in[5];
  const float* b_p   = (const float*)d_in[6];
  const float* w_r   = (const float*)d_in[7];
  const float* w_v   = (const float*)d_in[8];
  const float* b_v   = (const float*)d_in[9];
  float* out = (float*)d_out;

  k_pre<<<dim3(1024 + 352), 256, 0, stream>>>(nodes, w_v, w_n, out);
  k_mid<<<dim3(1792 + 512), 256, 0, stream>>>(b_v, b_n, pos, rot, w_p, b_p, w_r);
  k_attn<<<dim3(32, NHEAD), 256, 0, stream>>>(out);
}

// Round 17
// 161.925 us; speedup vs baseline: 1.2888x; 1.2834x over previous
//
#include <hip/hip_runtime.h>
#include <hip/hip_bf16.h>
#include <math.h>

#define SEQ 2048
#define NHEAD 24     // 3*H
#define CDIM 32
#define VDIM 128

typedef short bf16x8 __attribute__((ext_vector_type(8)));
typedef float f32x4 __attribute__((ext_vector_type(4)));

#define L2E 1.44269504088896f        // log2(e): folded into K so exp2 == exp
#define SQRT_L2E 1.20112240878645f   // sqrt(log2 e): rot logits get squared

#if __has_builtin(__builtin_amdgcn_exp2f)
#define EXP2(x) __builtin_amdgcn_exp2f(x)
#else
#define EXP2(x) exp2f(x)
#endif

// K B-frags, hi/lo split: [g][blk16(128)][part(2)][lane(64)][e(8)]
__device__ unsigned short g_kkp[(size_t)24 * 128 * 2 * 64 * 8];
// Q+V frags: [g][jt(32 x 64j)][frag(24)][lane(64)][e(8)]
__device__ unsigned short g_qv[(size_t)24 * 32 * 24 * 64 * 8];
// weights (w_values||w_nodes_kq rows): [fg(224*4)][part(2)][lane][e]
__device__ unsigned short g_wp[(size_t)224 * 4 * 2 * 64 * 8];
// nodes A-frags: [fg(128*4)][part(2)][lane][e]
__device__ unsigned short g_np[(size_t)128 * 4 * 2 * 64 * 8];

__device__ __forceinline__ unsigned short f2b(float x) {   // RNE f32->bf16
  union { float f; unsigned u; } v; v.f = x;
  unsigned r = v.u + 0x7FFF + ((v.u >> 16) & 1);
  return (unsigned short)(r >> 16);
}
__device__ __forceinline__ float b2f(unsigned short u) {
  union { unsigned u32; float f; } x; x.u32 = ((unsigned)u) << 16; return x.f;
}
__device__ __forceinline__ unsigned pk2(float a, float b) {
  __hip_bfloat162 t = __float22bfloat162_rn(float2{a, b});
  union { __hip_bfloat162 h; unsigned u; } c; c.h = t; return c.u;
}
__device__ __forceinline__ unsigned long long pack64(const float* p) {
  return ((unsigned long long)pk2(p[2], p[3]) << 32) | pk2(p[0], p[1]);
}
__device__ __forceinline__ float bperm_f(int srclane, float v) {
  union { float f; int i; } u; u.f = v;
  u.i = __builtin_amdgcn_ds_bpermute(srclane * 4, u.i);
  return u.f;
}
__device__ __forceinline__ void gld16(const unsigned short* g, unsigned short* l) {
  __builtin_amdgcn_global_load_lds(
      (const __attribute__((address_space(1))) unsigned int*)g,
      (__attribute__((address_space(3))) unsigned int*)l, 16, 0, 0);
}

// ---------- merged: zero d_out + one-shot hi/lo conversion of weights/nodes (r13) ----------
__global__ __launch_bounds__(256) void k_pre(const float* __restrict__ nodes,
                                             const float* __restrict__ w_v,
                                             const float* __restrict__ w_n,
                                             float* __restrict__ out) {
  const int bx = blockIdx.x;
  if (bx < 1024) { out[bx * 256 + threadIdx.x] = 0.f; return; }
  const int bb = bx - 1024;                 // 0..351
  const int tid = bb * 256 + threadIdx.x;
  const int fg = tid >> 6, lane = tid & 63;
  const int e0 = (lane >> 4) * 8;
  const float* p;
  unsigned short* dst;
  if (bb < 224) {
    const int colblk = fg >> 2, ks = fg & 3;
    const int ocol = colblk * 16 + (lane & 15);
    const float* src = (ocol < 3072) ? (w_v + (size_t)ocol * 128)
                                     : (w_n + (size_t)(ocol - 3072) * 128);
    p = src + ks * 32 + e0;
    dst = g_wp + (size_t)fg * 1024;
  } else {
    const int fg2 = fg - 224 * 4;           // 0..511
    const int rowblk = fg2 >> 2, ks = fg2 & 3;
    p = nodes + (size_t)(rowblk * 16 + (lane & 15)) * 128 + ks * 32 + e0;
    dst = g_np + (size_t)fg2 * 1024;
  }
  float4 f0 = *(const float4*)p;
  float4 f1 = *(const float4*)(p + 4);
  float ff[8] = {f0.x, f0.y, f0.z, f0.w, f1.x, f1.y, f1.z, f1.w};
  bf16x8 hi, lo;
#pragma unroll
  for (int e = 0; e < 8; ++e) {
    unsigned short h2 = f2b(ff[e]);
    hi[e] = (short)h2;
    lo[e] = (short)f2b(ff[e] - b2f(h2));
  }
  *(bf16x8*)(dst + (size_t)lane * 8) = hi;
  *(bf16x8*)(dst + 512 + (size_t)lane * 8) = lo;
}

// ---------- pos/rot repack helper (validated) ----------
__device__ __forceinline__ void repack_store(const unsigned* __restrict__ res,
                                             int oh, int it16, int tx, int head_base) {
#pragma unroll
  for (int t2 = 0; t2 < 2; ++t2) {
    int cid = tx + t2 * 256;
    int hl  = cid >> 7;
    int kq  = (cid >> 6) & 1;
    int row = cid & 63;
    int m = row & 15;
    int ob = hl * 64 + kq * 32 + (row >> 4) * 8;
    bf16x8 hi, lo;
#pragma unroll
    for (int e = 0; e < 8; ++e) {
      unsigned pk = res[(ob + e) * 17 + m];
      hi[e] = (short)(pk >> 16);
      lo[e] = (short)(pk & 0xffff);
    }
    int gh = head_base + oh * 4 + hl;
    if (kq == 0) {
      size_t base = ((size_t)(gh * 128 + it16) * 2) * 512 + (size_t)row * 8;
      *(bf16x8*)(g_kkp + base) = hi;
      *(bf16x8*)(g_kkp + base + 512) = lo;
    } else {
      int jt = it16 >> 2, jb = it16 & 3;
      size_t base = (((size_t)gh * 32 + jt) * 24 + jb * 2) * 512 + (size_t)row * 8;
      *(bf16x8*)(g_qv + base) = hi;
      *(bf16x8*)(g_qv + base + 512) = lo;
    }
  }
}

// ---------- merged: MFMA projection (bx<1792) + pos/rot (bx>=1792), smem overlaid (r13) ----------
__global__ __launch_bounds__(256) void k_mid(const float* __restrict__ b_v,
                                             const float* __restrict__ b_n,
                                             const float* __restrict__ pos,
                                             const float* __restrict__ rot,
                                             const float* __restrict__ w_p,
                                             const float* __restrict__ b_p,
                                             const float* __restrict__ w_r) {
  __shared__ __align__(16) char smem[53248];
  const int bx = blockIdx.x;
  const int tx = threadIdx.x;

  if (bx < 1792) {
    // ======== proj: C = nodes @ [w_values; w_nodes_kq]^T + bias (validated r10) ========
    const int jt = bx & 31;           // 64-row tile
    const int bo = bx >> 5;           // 64-col tile, 0..55
    const bool is_kq = bo >= 48;
    const float* bsrc = is_kq ? b_n : b_v;
    const int o0b = is_kq ? (bo - 48) * 64 : bo * 64;
    const int w = tx >> 6, lane = tx & 63;
    const int m = lane & 15, quad = lane >> 4;

    unsigned short (*bst)[64][8] = (unsigned short(*)[64][8])smem;       // 32 KB
    float (*res)[64][20] = (float(*)[64][20])(smem + 32768);             // 20 KB

    const unsigned short* wp = g_wp + ((size_t)bo * 32 + w * 8) * 512 + (size_t)lane * 8;
#pragma unroll
    for (int s = 0; s < 8; ++s)
      gld16(wp + s * 512, &bst[w * 8 + s][0][0]);

    bf16x8 ah[4], al[4];
    const unsigned short* np = g_np + (size_t)(jt * 4 + w) * 4096 + (size_t)lane * 8;
#pragma unroll
    for (int ks = 0; ks < 4; ++ks) {
      ah[ks] = *(const bf16x8*)(np + ks * 1024);
      al[ks] = *(const bf16x8*)(np + ks * 1024 + 512);
    }
    __syncthreads();

    f32x4 C[4];
#pragma unroll
    for (int ob = 0; ob < 4; ++ob) {
      f32x4 acc = {0.f, 0.f, 0.f, 0.f};
#pragma unroll
      for (int ks = 0; ks < 4; ++ks) {
        bf16x8 bh = *(const bf16x8*)&bst[ob * 8 + ks * 2][lane][0];
        bf16x8 bl = *(const bf16x8*)&bst[ob * 8 + ks * 2 + 1][lane][0];
        acc = __builtin_amdgcn_mfma_f32_16x16x32_bf16(ah[ks], bh, acc, 0, 0, 0);
        acc = __builtin_amdgcn_mfma_f32_16x16x32_bf16(al[ks], bh, acc, 0, 0, 0);
        acc = __builtin_amdgcn_mfma_f32_16x16x32_bf16(ah[ks], bl, acc, 0, 0, 0);
      }
      C[ob] = acc;
    }
#pragma unroll
    for (int ob = 0; ob < 4; ++ob) {
      float bias = bsrc[o0b + ob * 16 + m];
#pragma unroll
      for (int r = 0; r < 4; ++r)
        res[w][ob * 16 + m][quad * 4 + r] = C[ob][r] + bias;
    }
    if (!is_kq) {
      const int g = bo >> 1, dbb = (bo & 1) * 4;
      const int jc = w >> 1, khb = (w & 1) * 2;
#pragma unroll
      for (int oct = 0; oct < 2; ++oct) {
        f32x4 v0 = *(const f32x4*)&res[w][quad * 16 + m][oct * 8];
        f32x4 v1 = *(const f32x4*)&res[w][quad * 16 + m][oct * 8 + 4];
        bf16x8 pk;
#pragma unroll
        for (int e = 0; e < 4; ++e) {
          pk[e]     = (short)f2b(v0[e]);
          pk[4 + e] = (short)f2b(v1[e]);
        }
        ((bf16x8*)g_qv)[(((size_t)g * 32 + jt) * 24 + 8 + jc * 8 + dbb + quad) * 64
                        + (khb + oct) * 16 + m] = pk;
      }
    } else {
      const int h = bo - 48;
      {   // K (L2E folded)
        bf16x8 hi, lo;
#pragma unroll
        for (int e = 0; e < 8; ++e) {
          float v = res[w][quad * 8 + e][m] * L2E;
          unsigned short h2 = f2b(v);
          hi[e] = (short)h2;
          lo[e] = (short)f2b(v - b2f(h2));
        }
        size_t base = ((size_t)(h * 128 + jt * 4 + w) * 2) * 512 + (size_t)(quad * 16 + m) * 8;
        *(bf16x8*)(g_kkp + base) = hi;
        *(bf16x8*)(g_kkp + base + 512) = lo;
      }
      {   // Q
        bf16x8 hi, lo;
#pragma unroll
        for (int e = 0; e < 8; ++e) {
          float v = res[w][32 + quad * 8 + e][m];
          unsigned short h2 = f2b(v);
          hi[e] = (short)h2;
          lo[e] = (short)f2b(v - b2f(h2));
        }
        size_t base = (((size_t)h * 32 + jt) * 24 + w * 2) * 512 + (size_t)(quad * 16 + m) * 8;
        *(bf16x8*)(g_qv + base) = hi;
        *(bf16x8*)(g_qv + base + 512) = lo;
      }
    }
  } else {
    // ======== pos/rot (validated r10), smem overlay ========
    const int r0 = bx - 1792;                // 0..511
    const int it16 = r0 & 127, oh = (r0 >> 7) & 1, br = r0 >> 8;
    const int i0 = it16 * 16;
    unsigned* res = (unsigned*)smem;                         // 17408 B
    float (*pf_sh)[8] = (float(*)[8])(smem + 17408);
    float (*rr_sh)[4] = (float(*)[4])(smem + 17920);

    if (br == 0) {
      if (tx < 48) {
        int r = tx / 3, t = tx - r * 3;
        float p = pos[(i0 + r) * 3 + t];
        pf_sh[r][t]     = cosf(6.283185307179586f * p);
        pf_sh[r][t + 3] = sinf(6.283185307179586f * p);
      }
    } else {
      if (tx < 64) {
        int r = tx >> 2, t = tx & 3;
        rr_sh[r][t] = rot[(i0 + r) * 4 + t];
      }
    }
    __syncthreads();

    const int og = tx & 63, ig = tx >> 6;
    if (br == 0) {
#pragma unroll
      for (int oo = 0; oo < 4; ++oo) {
        int o = oh * 256 + oo * 64 + og;
        float bb = b_p[o];
        float w0 = w_p[o * 6 + 0], w1 = w_p[o * 6 + 1], w2 = w_p[o * 6 + 2];
        float w3 = w_p[o * 6 + 3], w4 = w_p[o * 6 + 4], w5 = w_p[o * 6 + 5];
        float sc = ((o & 63) < 32) ? L2E : 1.f;
#pragma unroll
        for (int ii = 0; ii < 4; ++ii) {
          int i = ig * 4 + ii;
          float v = bb + pf_sh[i][0] * w0 + pf_sh[i][1] * w1 + pf_sh[i][2] * w2
                       + pf_sh[i][3] * w3 + pf_sh[i][4] * w4 + pf_sh[i][5] * w5;
          v *= sc;
          unsigned short hi = f2b(v);
          unsigned short lo = f2b(v - b2f(hi));
          res[(oo * 64 + og) * 17 + i] = ((unsigned)hi << 16) | lo;
        }
      }
    } else {
#pragma unroll
      for (int oo = 0; oo < 4; ++oo) {
        int o = oh * 256 + oo * 64 + og;
        float w0 = w_r[o * 4 + 0], w1 = w_r[o * 4 + 1], w2 = w_r[o * 4 + 2], w3 = w_r[o * 4 + 3];
        float sc = ((o & 63) < 32) ? SQRT_L2E : 1.f;
#pragma unroll
        for (int ii = 0; ii < 4; ++ii) {
          int i = ig * 4 + ii;
          float v = (rr_sh[i][0] * w0 + rr_sh[i][1] * w1 + rr_sh[i][2] * w2 + rr_sh[i][3] * w3) * sc;
          unsigned short hi = f2b(v);
          unsigned short lo = f2b(v - b2f(hi));
          res[(oo * 64 + og) * 17 + i] = ((unsigned)hi << 16) | lo;
        }
      }
    }
    __syncthreads();
    repack_store(res, oh, it16, tx, 8 + br * 8);
  }
}

// ---------- MFMA flash attention: shift-free fast path (heads 0..15), online for rot ----------
__global__ __launch_bounds__(256, 3) void k_attn(float* __restrict__ out) {
  const int it = blockIdx.x;            // 0..31
  const int g  = blockIdx.y;            // 0..23
  const int tx = threadIdx.x;
  const int w = tx >> 6, lane = tx & 63;
  const int quad = lane >> 4, n = lane & 15;
  const int iblk = it * 4 + w;

  __shared__ __align__(16) unsigned short stage[2][24][64][8];   // 48 KB
  __shared__ __align__(16) unsigned long long p_lds[4][64][2];   // 4 KB

  const bf16x8* kp = (const bf16x8*)g_kkp + (size_t)(g * 128 + iblk) * 2 * 64;
  const bf16x8 khi = kp[lane], klo = kp[64 + lane];

  f32x4 oacc[8];
#pragma unroll
  for (int db = 0; db < 8; ++db)
#pragma unroll
    for (int r = 0; r < 4; ++r) oacc[db][r] = 0.f;

  const bool is_rot = (g >= 16);
  float l_part = 0.f;
  const int pin = (lane & 56) | ((lane ^ (lane >> 3)) & 7);
  const int wrow0 = (quad >> 1) * 16 + n;
  const int wrow1 = wrow0 + 32;
  const int pr0 = (wrow0 & 56) | ((wrow0 ^ (wrow0 >> 3)) & 7);
  const int pr1 = (wrow1 & 56) | ((wrow1 ^ (wrow1 >> 3)) & 7);
  const int whalf = quad & 1;

  const unsigned short* qv = g_qv + ((size_t)g * 32 * 24 + w * 6) * 512 + (size_t)lane * 8;

#define STG(nb)                                          \
  { gld16(qv,             &stage[nb][w * 6 + 0][0][0]);  \
    gld16(qv + 512,       &stage[nb][w * 6 + 1][0][0]);  \
    gld16(qv + 1024,      &stage[nb][w * 6 + 2][0][0]);  \
    gld16(qv + 1536,      &stage[nb][w * 6 + 3][0][0]);  \
    gld16(qv + 2048,      &stage[nb][w * 6 + 4][0][0]);  \
    gld16(qv + 2560,      &stage[nb][w * 6 + 5][0][0]); }

  STG(0)

  bf16x8 a0 = {}, a1 = {};
  bf16x8 vprev[16];

  if (!is_rot) {
    // ======== fast path: softmax is shift-invariant; logits bounded (|s|<~60 in log2,
    // f32 overflows only past 2^128) -> p = exp2(s) directly, no max tracking at all ========
    for (int jt = 0; jt < 32; ++jt) {
      const int buf = jt & 1;
      __syncthreads();
      if (jt) {
#pragma unroll
        for (int db = 0; db < 8; ++db)
          oacc[db] = __builtin_amdgcn_mfma_f32_16x16x32_bf16(a0, vprev[db], oacc[db], 0, 0, 0);
#pragma unroll
        for (int db = 0; db < 8; ++db)
          oacc[db] = __builtin_amdgcn_mfma_f32_16x16x32_bf16(a1, vprev[8 + db], oacc[db], 0, 0, 0);
      }
      qv += 24 * 512;
      if (jt < 31) STG(buf ^ 1)

      const bf16x8* st = (const bf16x8*)&stage[buf][0][0][0];
      f32x4 S[4];
#pragma unroll
      for (int jb = 0; jb < 4; ++jb) {
        bf16x8 qh = st[(jb * 2) * 64 + lane], ql = st[(jb * 2 + 1) * 64 + lane];
        f32x4 a = {0.f, 0.f, 0.f, 0.f};
        a = __builtin_amdgcn_mfma_f32_16x16x32_bf16(qh, khi, a, 0, 0, 0);
        a = __builtin_amdgcn_mfma_f32_16x16x32_bf16(ql, khi, a, 0, 0, 0);
        a = __builtin_amdgcn_mfma_f32_16x16x32_bf16(qh, klo, a, 0, 0, 0);
        S[jb] = a;
      }
      float p[4][4];
#pragma unroll
      for (int jb = 0; jb < 4; ++jb)
#pragma unroll
        for (int r = 0; r < 4; ++r) {
          p[jb][r] = EXP2(S[jb][r]);
          l_part += p[jb][r];
        }
      p_lds[w][pr0][whalf] = pack64(p[0]);
      p_lds[w][pr1][whalf] = pack64(p[1]);
      a0 = *(const bf16x8*)&p_lds[w][pin][0];
      p_lds[w][pr0][whalf] = pack64(p[2]);
      p_lds[w][pr1][whalf] = pack64(p[3]);
      a1 = *(const bf16x8*)&p_lds[w][pin][0];
#pragma unroll
      for (int f = 0; f < 16; ++f) vprev[f] = st[(8 + f) * 64 + lane];
    }
  } else {
    // ======== rot heads: squared logits can reach ~2^190 -> keep online-softmax (r13) ========
    float m_run = -3.0e38f;
    for (int jt = 0; jt < 32; ++jt) {
      const int buf = jt & 1;
      __syncthreads();
      if (jt) {
#pragma unroll
        for (int db = 0; db < 8; ++db)
          oacc[db] = __builtin_amdgcn_mfma_f32_16x16x32_bf16(a0, vprev[db], oacc[db], 0, 0, 0);
#pragma unroll
        for (int db = 0; db < 8; ++db)
          oacc[db] = __builtin_amdgcn_mfma_f32_16x16x32_bf16(a1, vprev[8 + db], oacc[db], 0, 0, 0);
      }
      qv += 24 * 512;
      if (jt < 31) STG(buf ^ 1)

      const bf16x8* st = (const bf16x8*)&stage[buf][0][0][0];
      f32x4 S[4];
#pragma unroll
      for (int jb = 0; jb < 4; ++jb) {
        bf16x8 qh = st[(jb * 2) * 64 + lane], ql = st[(jb * 2 + 1) * 64 + lane];
        f32x4 a = {0.f, 0.f, 0.f, 0.f};
        a = __builtin_amdgcn_mfma_f32_16x16x32_bf16(qh, khi, a, 0, 0, 0);
        a = __builtin_amdgcn_mfma_f32_16x16x32_bf16(ql, khi, a, 0, 0, 0);
        a = __builtin_amdgcn_mfma_f32_16x16x32_bf16(qh, klo, a, 0, 0, 0);
        S[jb] = a;
      }
#pragma unroll
      for (int jb = 0; jb < 4; ++jb)
#pragma unroll
        for (int r = 0; r < 4; ++r) S[jb][r] *= S[jb][r];
      float mloc = S[0][0];
#pragma unroll
      for (int jb = 0; jb < 4; ++jb)
#pragma unroll
        for (int r = 0; r < 4; ++r) mloc = fmaxf(mloc, S[jb][r]);
      if (__ballot(mloc > m_run)) {
        float mb = fmaxf(mloc, __shfl_xor(mloc, 16));
        mb = fmaxf(mb, __shfl_xor(mb, 32));
        float m_new = fmaxf(m_run, mb);
        float alpha = EXP2(m_run - m_new);
        m_run = m_new;
        l_part *= alpha;
        f32x4 av;
#pragma unroll
        for (int r = 0; r < 4; ++r) av[r] = bperm_f(quad * 4 + r, alpha);
#pragma unroll
        for (int db = 0; db < 8; ++db) {
          oacc[db][0] *= av[0]; oacc[db][1] *= av[1];
          oacc[db][2] *= av[2]; oacc[db][3] *= av[3];
        }
      }
      float p[4][4];
#pragma unroll
      for (int jb = 0; jb < 4; ++jb)
#pragma unroll
        for (int r = 0; r < 4; ++r) {
          p[jb][r] = EXP2(S[jb][r] - m_run);
          l_part += p[jb][r];
        }
      p_lds[w][pr0][whalf] = pack64(p[0]);
      p_lds[w][pr1][whalf] = pack64(p[1]);
      a0 = *(const bf16x8*)&p_lds[w][pin][0];
      p_lds[w][pr0][whalf] = pack64(p[2]);
      p_lds[w][pr1][whalf] = pack64(p[3]);
      a1 = *(const bf16x8*)&p_lds[w][pin][0];
#pragma unroll
      for (int f = 0; f < 16; ++f) vprev[f] = st[(8 + f) * 64 + lane];
    }
  }
  // --- final PV(31)
#pragma unroll
  for (int db = 0; db < 8; ++db)
    oacc[db] = __builtin_amdgcn_mfma_f32_16x16x32_bf16(a0, vprev[db], oacc[db], 0, 0, 0);
#pragma unroll
  for (int db = 0; db < 8; ++db)
    oacc[db] = __builtin_amdgcn_mfma_f32_16x16x32_bf16(a1, vprev[8 + db], oacc[db], 0, 0, 0);

  // --- epilogue: l reduction, column->row broadcast, scaled atomics
  float l = l_part;
  l += __shfl_xor(l, 16);
  l += __shfl_xor(l, 32);
  float linv = 1.f / l;
  f32x4 lv;
#pragma unroll
  for (int r = 0; r < 4; ++r) lv[r] = bperm_f(quad * 4 + r, linv);
  const int ibase = it * 64 + w * 16 + quad * 4;
#pragma unroll
  for (int db = 0; db < 8; ++db)
#pragma unroll
    for (int r = 0; r < 4; ++r)
      atomicAdd(&out[(size_t)(ibase + r) * VDIM + db * 16 + n], oacc[db][r] * lv[r]);
}

extern "C" void kernel_launch(void* const* d_in, const int* in_sizes, int n_in,
                              void* d_out, int out_size, void* d_ws, size_t ws_size,
                              hipStream_t stream) {
  const float* nodes = (const float*)d_in[0];
  const float* pos   = (const float*)d_in[1];
  const float* rot   = (const float*)d_in[2];
  const float* w_n   = (const float*)d_in[3];
  const float* b_n   = (const float*)d_in[4];
  const float* w_p   = (const float*)d_in[5];
  const float* b_p   = (const float*)d_in[6];
  const float* w_r   = (const float*)d_in[7];
  const float* w_v   = (const float*)d_in[8];
  const float* b_v   = (const float*)d_in[9];
  float* out = (float*)d_out;

  k_pre<<<dim3(1024 + 352), 256, 0, stream>>>(nodes, w_v, w_n, out);
  k_mid<<<dim3(1792 + 512), 256, 0, stream>>>(b_v, b_n, pos, rot, w_p, b_p, w_r);
  k_attn<<<dim3(32, NHEAD), 256, 0, stream>>>(out);
}